// Round 2
// baseline (960.379 us; speedup 1.0000x reference)
//
#include <hip/hip_runtime.h>
#include <math.h>

#define NN 8192
#define DD 256
#define TOPK 64
#define CAP 68            // survivor capacity per row (64 + tie paranoia)
#define NEGVAL (-1000000000.0f)

// ---------------------------------------------------------------------------
// NT GEMM  C[M][Ncols] = A[M][DD] * B[Ncols][DD]^T  (+bias | scale+diag)
// 128x128 tile, BK=32, 256 threads, 8x8 micro-tile per thread. M = grid.x*128.
// For the scores GEMM: C rows are chunk-local; global row = rowOff + local.
// ---------------------------------------------------------------------------
__global__ __launch_bounds__(256)
void gemm_nt_f32(const float* __restrict__ A, const float* __restrict__ B,
                 float* __restrict__ C, int ldc,
                 const float* __restrict__ bias,
                 const float* __restrict__ temp, int diagNeg, int rowOff)
{
  __shared__ float As[32][128];
  __shared__ float Bs[32][128];
  const int t  = threadIdx.x;
  const int tm = t & 15;
  const int tn = t >> 4;
  const int m0 = blockIdx.x * 128;
  const int n0 = blockIdx.y * 128;

  float acc[8][8];
#pragma unroll
  for (int i = 0; i < 8; ++i)
#pragma unroll
    for (int j = 0; j < 8; ++j) acc[i][j] = 0.0f;

  for (int k0 = 0; k0 < DD; k0 += 32) {
#pragma unroll
    for (int i = 0; i < 4; ++i) {
      int idx = t + i * 256;          // 0..1023 float4 slots per tile
      int row = idx >> 3;             // 0..127
      int c4  = (idx & 7) << 2;       // 0,4,..,28
      float4 av = *(const float4*)(A + (size_t)(m0 + row) * DD + k0 + c4);
      float4 bv = *(const float4*)(B + (size_t)(n0 + row) * DD + k0 + c4);
      As[c4 + 0][row] = av.x; As[c4 + 1][row] = av.y;
      As[c4 + 2][row] = av.z; As[c4 + 3][row] = av.w;
      Bs[c4 + 0][row] = bv.x; Bs[c4 + 1][row] = bv.y;
      Bs[c4 + 2][row] = bv.z; Bs[c4 + 3][row] = bv.w;
    }
    __syncthreads();
#pragma unroll
    for (int kk = 0; kk < 32; ++kk) {
      float a[8], b[8];
      *(float4*)&a[0] = *(const float4*)&As[kk][tm * 4];
      *(float4*)&a[4] = *(const float4*)&As[kk][64 + tm * 4];
      *(float4*)&b[0] = *(const float4*)&Bs[kk][tn * 4];
      *(float4*)&b[4] = *(const float4*)&Bs[kk][64 + tn * 4];
#pragma unroll
      for (int i = 0; i < 8; ++i)
#pragma unroll
        for (int j = 0; j < 8; ++j)
          acc[i][j] = fmaf(a[i], b[j], acc[i][j]);
    }
    __syncthreads();
  }

  const bool doScale = (temp != nullptr);
  const float tscale = doScale ? (temp[0] * 16.0f) : 1.0f;  // temp * sqrt(256)

#pragma unroll
  for (int gi = 0; gi < 2; ++gi)
#pragma unroll
    for (int r = 0; r < 4; ++r) {
      const int lrow = gi * 64 + tm * 4 + r;           // local C row
      const int grow = rowOff + m0 + lrow;             // global score row
#pragma unroll
      for (int gj = 0; gj < 2; ++gj) {
        const int gcol0 = n0 + gj * 64 + tn * 4;
        float v[4];
#pragma unroll
        for (int c = 0; c < 4; ++c) {
          float x = acc[gi * 4 + r][gj * 4 + c];
          if (doScale) x = x / tscale;
          if (bias)    x += bias[gcol0 + c];
          if (diagNeg && grow == (gcol0 + c)) x = NEGVAL;
          v[c] = x;
        }
        *(float4*)(C + (size_t)(m0 + lrow) * ldc + gcol0) =
            make_float4(v[0], v[1], v[2], v[3]);
      }
    }
}

// ---------------------------------------------------------------------------
// Fused exact top-64 threshold + softmax weights. One 256-thread block per
// row. Row staged in LDS as order-preserving uint keys; 4-level radix select
// gives the EXACT 64th-largest value (ties counted). Survivors (key >= thr,
// includes ties) compacted deterministically (prefix-sum, j-order), softmax'd
// against the row max, normalized weights + indices written out.
// ---------------------------------------------------------------------------
__global__ __launch_bounds__(256)
void topk_softmax(const float* __restrict__ Sc, int rowOff,
                  float* __restrict__ wts, int* __restrict__ idx,
                  int* __restrict__ cnt)
{
  __shared__ unsigned keys[NN];
  __shared__ unsigned hist[256];
  __shared__ int      pfx[256];
  __shared__ float    pb[CAP];
  __shared__ int      jb[CAP];
  __shared__ unsigned smax, sbin, srank;
  __shared__ float    spsum;
  const int t = threadIdx.x;
  const int grow = rowOff + blockIdx.x;
  const float* srow = Sc + (size_t)blockIdx.x * NN;

  if (t == 0) { smax = 0u; spsum = 0.0f; }
  unsigned mymax = 0u;
  for (int j = t; j < NN; j += 256) {
    unsigned b = __float_as_uint(srow[j]);
    unsigned u = (b & 0x80000000u) ? ~b : (b | 0x80000000u);  // order-preserving
    keys[j] = u;
    mymax = (u > mymax) ? u : mymax;
  }
  __syncthreads();
  atomicMax(&smax, mymax);
  __syncthreads();

  // 4-level radix select for rank TOPK (largest)
  unsigned prefix = 0u;
  unsigned rank = TOPK;
  for (int level = 0; level < 4; ++level) {
    const int shift = 24 - 8 * level;
    hist[t] = 0u;
    __syncthreads();
    const unsigned pmask = (level == 0) ? 0u : (0xFFFFFFFFu << (shift + 8));
    for (int j = t; j < NN; j += 256) {
      unsigned u = keys[j];
      if ((u & pmask) == prefix)
        atomicAdd(&hist[(u >> shift) & 255u], 1u);
    }
    __syncthreads();
    // inclusive suffix sum: hist[b] := count with bin >= b
    for (int st = 1; st < 256; st <<= 1) {
      unsigned add = (t + st < 256) ? hist[t + st] : 0u;
      __syncthreads();
      hist[t] += add;
      __syncthreads();
    }
    unsigned s_here = hist[t];
    unsigned s_next = (t == 255) ? 0u : hist[t + 1];
    if (s_here >= rank && s_next < rank) { sbin = (unsigned)t; srank = rank - s_next; }
    __syncthreads();
    prefix |= (sbin << shift);
    rank = srank;
    __syncthreads();
  }
  const unsigned uthr = prefix;                 // exact key of 64th-largest
  const unsigned um = smax;
  const float m = __uint_as_float((um & 0x80000000u) ? (um & 0x7FFFFFFFu) : ~um);

  // deterministic compaction: thread t owns j in [t*32, t*32+32)
  int c = 0;
  const int j0 = t * 32;
#pragma unroll 4
  for (int j = j0; j < j0 + 32; ++j) c += (keys[j] >= uthr) ? 1 : 0;
  pfx[t] = c;
  __syncthreads();
  for (int st = 1; st < 256; st <<= 1) {
    int add = (t >= st) ? pfx[t - st] : 0;
    __syncthreads();
    pfx[t] += add;
    __syncthreads();
  }
  int base = pfx[t] - c;                        // exclusive prefix
  const int total = pfx[255];
  for (int j = j0; j < j0 + 32; ++j) {
    unsigned u = keys[j];
    if (u >= uthr) {
      if (base < CAP) {
        float s = __uint_as_float((u & 0x80000000u) ? (u & 0x7FFFFFFFu) : ~u);
        pb[base] = __expf(s - m);
        jb[base] = j;
      }
      ++base;
    }
  }
  __syncthreads();
  const int L = (total < CAP) ? total : CAP;
  if (t == 0) {
    float ps = 0.0f;
    for (int i = 0; i < L; ++i) ps += pb[i];
    spsum = ps;
  }
  __syncthreads();
  const float inv = 1.0f / spsum;
  for (int i = t; i < L; i += 256) {
    wts[(size_t)grow * CAP + i] = pb[i] * inv;
    idx[(size_t)grow * CAP + i] = jb[i];
  }
  if (t == 0) cnt[grow] = L;
}

// ---------------------------------------------------------------------------
// Sparse AV: out[row][t] = sum_i wts[row][i] * V[idx[row][i]][t]
// ---------------------------------------------------------------------------
__global__ __launch_bounds__(256)
void sparse_av(const float* __restrict__ V, const float* __restrict__ wts,
               const int* __restrict__ idx, const int* __restrict__ cnt,
               float* __restrict__ out)
{
  __shared__ float  wl[CAP];
  __shared__ int    jl[CAP];
  const int t = threadIdx.x;
  const int row = blockIdx.x;
  const int L = cnt[row];
  if (t < CAP && t < L) {
    wl[t] = wts[(size_t)row * CAP + t];
    jl[t] = idx[(size_t)row * CAP + t];
  }
  __syncthreads();
  float acc = 0.0f;
  for (int i = 0; i < L; ++i)
    acc = fmaf(wl[i], V[(size_t)jl[i] * DD + t], acc);
  out[(size_t)row * DD + t] = acc;
}

// ---------------------------------------------------------------------------
extern "C" void kernel_launch(void* const* d_in, const int* in_sizes, int n_in,
                              void* d_out, int out_size, void* d_ws, size_t ws_size,
                              hipStream_t stream)
{
  const float* X    = (const float*)d_in[0];
  const float* Wq   = (const float*)d_in[1];
  const float* bq   = (const float*)d_in[2];
  const float* Wk   = (const float*)d_in[3];
  const float* bk   = (const float*)d_in[4];
  const float* Wv   = (const float*)d_in[5];
  const float* bv   = (const float*)d_in[6];
  const float* temp = (const float*)d_in[7];
  float* out = (float*)d_out;
  float* ws  = (float*)d_ws;

  const size_t avail = ws_size / sizeof(float);

  // fixed allocations (floats)
  const size_t szKV   = (size_t)NN * DD;       // K buffer, later reused for V
  const size_t szWts  = (size_t)NN * CAP;
  const size_t szIdx  = (size_t)NN * CAP;
  const size_t szCnt  = NN;
  const size_t fixed1 = szKV + szWts + szIdx + szCnt;

  // tier A: full Q resident; tier B: per-chunk Q
  const size_t needA = fixed1 + (size_t)NN * DD + (size_t)128 * NN;
  const size_t needB = fixed1 + (size_t)128 * DD + (size_t)128 * NN;
  const bool tierA = (avail >= needA);
  if (!tierA && avail < needB) return;  // < ~16.6 MB scratch: cannot proceed

  size_t o = 0;
  float* Kbuf = ws + o; o += szKV;      // K, then V
  float* wts  = ws + o; o += szWts;
  int*   idxb = (int*)(ws + o); o += szIdx;
  int*   cntb = (int*)(ws + o); o += szCnt;

  float* Qbuf;
  int CR;
  if (tierA) {
    Qbuf = ws + o; o += (size_t)NN * DD;
    size_t rem = avail - o;
    CR = (int)((rem / NN) / 128) * 128;
  } else {
    size_t rem = avail - o;
    CR = (int)((rem / (NN + DD)) / 128) * 128;
    Qbuf = ws + o; o += (size_t)CR * DD;
  }
  if (CR > NN) CR = NN;
  if (CR < 128) return;
  float* Sc = ws + o;                   // CR x NN chunk of scores

  dim3 blk(256);

  // K = X @ Wk^T + bk
  gemm_nt_f32<<<dim3(NN/128, DD/128), blk, 0, stream>>>(X, Wk, Kbuf, DD, bk, nullptr, 0, 0);
  if (tierA) {
    // full Q = X @ Wq^T + bq
    gemm_nt_f32<<<dim3(NN/128, DD/128), blk, 0, stream>>>(X, Wq, Qbuf, DD, bq, nullptr, 0, 0);
  }

  for (int r0 = 0; r0 < NN; r0 += CR) {
    const int rows = (NN - r0 < CR) ? (NN - r0) : CR;
    const float* Qrows;
    if (tierA) {
      Qrows = Qbuf + (size_t)r0 * DD;
    } else {
      gemm_nt_f32<<<dim3(rows/128, DD/128), blk, 0, stream>>>(
          X + (size_t)r0 * DD, Wq, Qbuf, DD, bq, nullptr, 0, 0);
      Qrows = Qbuf;
    }
    // Sc = Qrows @ K^T / (temp*16), diagonal -> NEG
    gemm_nt_f32<<<dim3(rows/128, NN/128), blk, 0, stream>>>(
        Qrows, Kbuf, Sc, NN, nullptr, temp, 1, r0);
    // exact top-64 threshold + softmax weights
    topk_softmax<<<dim3(rows), blk, 0, stream>>>(Sc, r0, wts, idxb, cntb);
  }

  // V = X @ Wv^T + bv  (overwrites K, which is no longer needed)
  float* Vbuf = Kbuf;
  gemm_nt_f32<<<dim3(NN/128, DD/128), blk, 0, stream>>>(X, Wv, Vbuf, DD, bv, nullptr, 0, 0);

  // out = sparse attn @ V
  sparse_av<<<dim3(NN), blk, 0, stream>>>(Vbuf, wts, idxb, cntb, out);
}

// Round 3
// 431.979 us; speedup vs baseline: 2.2232x; 2.2232x over previous
//
#include <hip/hip_runtime.h>
#include <math.h>

#define NN 8192
#define DD 256
#define TOPK 64
#define CAP 96            // survivor capacity per row
#define CCAP 256          // candidate capacity for exact select
#define NEGVAL (-1000000000.0f)

typedef _Float16 f16;
typedef f16  f16x8 __attribute__((ext_vector_type(8)));
typedef float f32x4 __attribute__((ext_vector_type(4)));

// ---------------------------------------------------------------------------
// f32 NT GEMM for QKV projections (8192x256x256): C = A @ B^T + bias
// 128x128 tile, BK=32, 256 threads, 8x8 micro-tile. (Proven in R2.)
// ---------------------------------------------------------------------------
__global__ __launch_bounds__(256)
void gemm_nt_f32(const float* __restrict__ A, const float* __restrict__ B,
                 float* __restrict__ C, int ldc, const float* __restrict__ bias)
{
  __shared__ float As[32][128];
  __shared__ float Bs[32][128];
  const int t  = threadIdx.x;
  const int tm = t & 15;
  const int tn = t >> 4;
  const int m0 = blockIdx.x * 128;
  const int n0 = blockIdx.y * 128;

  float acc[8][8];
#pragma unroll
  for (int i = 0; i < 8; ++i)
#pragma unroll
    for (int j = 0; j < 8; ++j) acc[i][j] = 0.0f;

  for (int k0 = 0; k0 < DD; k0 += 32) {
#pragma unroll
    for (int i = 0; i < 4; ++i) {
      int idx = t + i * 256;
      int row = idx >> 3;
      int c4  = (idx & 7) << 2;
      float4 av = *(const float4*)(A + (size_t)(m0 + row) * DD + k0 + c4);
      float4 bv = *(const float4*)(B + (size_t)(n0 + row) * DD + k0 + c4);
      As[c4 + 0][row] = av.x; As[c4 + 1][row] = av.y;
      As[c4 + 2][row] = av.z; As[c4 + 3][row] = av.w;
      Bs[c4 + 0][row] = bv.x; Bs[c4 + 1][row] = bv.y;
      Bs[c4 + 2][row] = bv.z; Bs[c4 + 3][row] = bv.w;
    }
    __syncthreads();
#pragma unroll
    for (int kk = 0; kk < 32; ++kk) {
      float a[8], b[8];
      *(float4*)&a[0] = *(const float4*)&As[kk][tm * 4];
      *(float4*)&a[4] = *(const float4*)&As[kk][64 + tm * 4];
      *(float4*)&b[0] = *(const float4*)&Bs[kk][tn * 4];
      *(float4*)&b[4] = *(const float4*)&Bs[kk][64 + tn * 4];
#pragma unroll
      for (int i = 0; i < 8; ++i)
#pragma unroll
        for (int j = 0; j < 8; ++j)
          acc[i][j] = fmaf(a[i], b[j], acc[i][j]);
    }
    __syncthreads();
  }

#pragma unroll
  for (int gi = 0; gi < 2; ++gi)
#pragma unroll
    for (int r = 0; r < 4; ++r) {
      const int grow = m0 + gi * 64 + tm * 4 + r;
#pragma unroll
      for (int gj = 0; gj < 2; ++gj) {
        const int gcol0 = n0 + gj * 64 + tn * 4;
        float v[4];
#pragma unroll
        for (int c = 0; c < 4; ++c)
          v[c] = acc[gi * 4 + r][gj * 4 + c] + (bias ? bias[gcol0 + c] : 0.0f);
        *(float4*)(C + (size_t)grow * ldc + gcol0) =
            make_float4(v[0], v[1], v[2], v[3]);
      }
    }
}

// ---------------------------------------------------------------------------
// Split Q,K (f32) into f16 hi/lo, laid out K-dim-768:
//   Qs[row] = [Qhi(256) | Qhi(256) | Qlo(256)]
//   Ks[row] = [Khi(256) | Klo(256) | Khi(256)]
// so that sum over 768 = Qhi*Khi + Qhi*Klo + Qlo*Khi  (lo*lo dropped, ~2^-22)
// ---------------------------------------------------------------------------
__global__ __launch_bounds__(256)
void cvt_hilo(const float* __restrict__ Q, const float* __restrict__ Kf,
              f16* __restrict__ Qs, f16* __restrict__ Ks)
{
  const size_t i = (size_t)blockIdx.x * 256 + threadIdx.x;  // over NN*DD
  const int r = (int)(i >> 8);
  const int c = (int)(i & 255);
  float q = Q[i];
  f16 qh = (f16)q;
  f16 ql = (f16)(q - (float)qh);
  Qs[(size_t)r * 768 + c]       = qh;
  Qs[(size_t)r * 768 + 256 + c] = qh;
  Qs[(size_t)r * 768 + 512 + c] = ql;
  float k = Kf[i];
  f16 kh = (f16)k;
  f16 kl = (f16)(k - (float)kh);
  Ks[(size_t)r * 768 + c]       = kh;
  Ks[(size_t)r * 768 + 256 + c] = kl;
  Ks[(size_t)r * 768 + 512 + c] = kh;
}

// ---------------------------------------------------------------------------
// MFMA scores GEMM: Sc[m][n] = (sum_k Aq[m][k]*Bk[n][k]) * invts, diag -> NEG
// m97 structure: 128x128 tile, BK=64, 4 waves (2x2 of 64x64), f16 16x16x32,
// global_load_lds width 16 staging, 8 ds_read_b128 + 16 MFMA per half-step.
// ---------------------------------------------------------------------------
typedef __attribute__((address_space(1))) const void GV;
typedef __attribute__((address_space(3))) void LV;
__device__ __forceinline__ void gl_lds16(const void* g, void* l) {
  __builtin_amdgcn_global_load_lds((GV*)g, (LV*)l, 16, 0, 0);
}

__global__ __launch_bounds__(256)
void gemm_scores_f16(const f16* __restrict__ Aq, const f16* __restrict__ Bk,
                     float* __restrict__ C, const float* __restrict__ temp,
                     int rowOff)
{
  __shared__ __align__(16) f16 As[128 * 64];
  __shared__ __align__(16) f16 Bs[128 * 64];
  const int t  = threadIdx.x;
  const int l  = t & 63;
  const int w  = t >> 6;          // wave 0..3
  const int wr = w >> 1;          // wave row quadrant
  const int wc = w & 1;           // wave col quadrant
  const int m0 = blockIdx.x * 128;
  const int n0 = blockIdx.y * 128;

  f32x4 acc[4][4];
#pragma unroll
  for (int m = 0; m < 4; ++m)
#pragma unroll
    for (int n = 0; n < 4; ++n) acc[m][n] = (f32x4){0.f, 0.f, 0.f, 0.f};

  const int lr = l >> 3;          // staging: row within 8-row segment
  const int lk = (l & 7) * 8;     // staging: k offset (f16)
  const int fr = l & 15;          // fragment row/col
  const int fg = l >> 4;          // fragment k-group (0..3)

  for (int k0 = 0; k0 < 768; k0 += 64) {
    __syncthreads();              // previous compute done before overwrite
#pragma unroll
    for (int i = 0; i < 4; ++i) {
      const int seg = w * 4 + i;  // 0..15, covers rows seg*8..seg*8+7
      gl_lds16(Aq + (size_t)(m0 + seg * 8 + lr) * 768 + k0 + lk, &As[seg * 512]);
      gl_lds16(Bk + (size_t)(n0 + seg * 8 + lr) * 768 + k0 + lk, &Bs[seg * 512]);
    }
    __syncthreads();              // compiler drains vmcnt before barrier
#pragma unroll
    for (int kk = 0; kk < 2; ++kk) {
      f16x8 af[4], bf[4];
#pragma unroll
      for (int m = 0; m < 4; ++m)
        af[m] = *(const f16x8*)&As[(wr * 64 + m * 16 + fr) * 64 + kk * 32 + fg * 8];
#pragma unroll
      for (int n = 0; n < 4; ++n)
        bf[n] = *(const f16x8*)&Bs[(wc * 64 + n * 16 + fr) * 64 + kk * 32 + fg * 8];
#pragma unroll
      for (int m = 0; m < 4; ++m)
#pragma unroll
        for (int n = 0; n < 4; ++n)
          acc[m][n] = __builtin_amdgcn_mfma_f32_16x16x32_f16(af[m], bf[n], acc[m][n], 0, 0, 0);
    }
  }

  const float invts = 1.0f / (temp[0] * 16.0f);
#pragma unroll
  for (int m = 0; m < 4; ++m)
#pragma unroll
    for (int n = 0; n < 4; ++n) {
      const int gcol = n0 + wc * 64 + n * 16 + fr;    // C/D: col = lane&15
#pragma unroll
      for (int j = 0; j < 4; ++j) {                   // row = (lane>>4)*4 + j
        const int lrow = m0 + wr * 64 + m * 16 + fg * 4 + j;
        float x = acc[m][n][j] * invts;
        if (rowOff + lrow == gcol) x = NEGVAL;
        C[(size_t)lrow * NN + gcol] = x;
      }
    }
}

// ---------------------------------------------------------------------------
// topk_softmax v2: row in registers (32 f32/thread). Block max via shuffles;
// value-quantized histogram over [lo, m] (only s>=lo enter -> low contention);
// suffix-scan -> boundary bin -> exact 64th-largest among ~66 candidates via
// count-greater; survivors (s >= T, ties incl.) compacted deterministically.
// ---------------------------------------------------------------------------
__global__ __launch_bounds__(256)
void topk_softmax2(const float* __restrict__ Sc, int rowOff,
                   float* __restrict__ wts, int* __restrict__ idx,
                   int* __restrict__ cnt)
{
  __shared__ unsigned hist[256];
  __shared__ int      pfx[256];
  __shared__ float    candv[CCAP];
  __shared__ float    pb[CAP];
  __shared__ int      jb[CAP];
  __shared__ float    wmax[4], wsum[4];
  __shared__ int      sB, candn;
  __shared__ unsigned uT;

  const int t = threadIdx.x;
  const int l = t & 63;
  const int w = t >> 6;
  const int grow = rowOff + blockIdx.x;
  const float* srow = Sc + (size_t)blockIdx.x * NN;

  float v[32];
#pragma unroll
  for (int c = 0; c < 8; ++c) {
    float4 f = *(const float4*)(srow + ((size_t)c * 256 + t) * 4);
    v[c * 4 + 0] = f.x; v[c * 4 + 1] = f.y; v[c * 4 + 2] = f.z; v[c * 4 + 3] = f.w;
  }
  // element index of v[c*4+q] = (c*256 + t)*4 + q

  // ---- block max ----
  float lm = -3.0e38f;
#pragma unroll
  for (int r = 0; r < 32; ++r) lm = fmaxf(lm, v[r]);
#pragma unroll
  for (int off = 32; off; off >>= 1) lm = fmaxf(lm, __shfl_xor(lm, off));
  if (l == 0) wmax[w] = lm;
  __syncthreads();
  const float m = fmaxf(fmaxf(wmax[0], wmax[1]), fmaxf(wmax[2], wmax[3]));

  // ---- histogram over [lo, m], widen if fewer than TOPK values >= lo ----
  float lo = m - 2.5f;
  int B = -1;
  for (int iter = 0; iter < 8; ++iter) {
    hist[t] = 0u;
    __syncthreads();
    const float invw = 256.0f / (m - lo);
#pragma unroll
    for (int r = 0; r < 32; ++r) {
      float s = v[r];
      if (s >= lo) {
        int b = (int)((s - lo) * invw);
        b = (b > 255) ? 255 : b;
        atomicAdd(&hist[b], 1u);
      }
    }
    __syncthreads();
    for (int st = 1; st < 256; st <<= 1) {      // suffix sum: hist[b]=#(bin>=b)
      unsigned add = (t + st < 256) ? hist[t + st] : 0u;
      __syncthreads();
      hist[t] += add;
      __syncthreads();
    }
    if (hist[0] >= TOPK) {
      unsigned here = hist[t];
      unsigned nxt = (t == 255) ? 0u : hist[t + 1];
      if (here >= TOPK && nxt < TOPK) sB = t;
      __syncthreads();
      B = sB;
      break;
    }
    __syncthreads();
    lo = m - 2.5f * (float)(2 << iter);          // -5, -10, -20, -40 ...
  }
  if (B < 0) B = 0;  // unreachable in practice

  // ---- collect candidates (bin >= B) ----
  if (t == 0) candn = 0;
  __syncthreads();
  {
    const float invw = 256.0f / (m - lo);
#pragma unroll
    for (int r = 0; r < 32; ++r) {
      float s = v[r];
      if (s >= lo) {
        int b = (int)((s - lo) * invw);
        b = (b > 255) ? 255 : b;
        if (b >= B) {
          int p = atomicAdd(&candn, 1);
          if (p < CCAP) candv[p] = s;
        }
      }
    }
  }
  __syncthreads();
  const int L = (candn < CCAP) ? candn : CCAP;

  // ---- exact 64th-largest among candidates: T = min{v_i : #(>v_i) <= 63} ----
  if (t == 0) uT = 0xFFFFFFFFu;
  __syncthreads();
  for (int i = t; i < L; i += 256) {
    float vi = candv[i];
    int g = 0;
    for (int j = 0; j < L; ++j) g += (candv[j] > vi) ? 1 : 0;
    if (g <= TOPK - 1) {
      unsigned ub = __float_as_uint(vi);
      unsigned u = (ub & 0x80000000u) ? ~ub : (ub | 0x80000000u);  // monotone
      atomicMin(&uT, u);
    }
  }
  __syncthreads();
  const unsigned uth = uT;
  const float T = __uint_as_float((uth & 0x80000000u) ? (uth & 0x7FFFFFFFu) : ~uth);

  // ---- deterministic survivor compaction (s >= T, ties included) ----
  int myc = 0;
#pragma unroll
  for (int r = 0; r < 32; ++r) myc += (v[r] >= T) ? 1 : 0;
  pfx[t] = myc;
  __syncthreads();
  for (int st = 1; st < 256; st <<= 1) {
    int add = (t >= st) ? pfx[t - st] : 0;
    __syncthreads();
    pfx[t] += add;
    __syncthreads();
  }
  int base = pfx[t] - myc;
  const int total = pfx[255];
#pragma unroll
  for (int r = 0; r < 32; ++r) {
    if (v[r] >= T) {
      if (base < CAP) {
        pb[base] = __expf(v[r] - m);
        jb[base] = ((r >> 2) * 256 + t) * 4 + (r & 3);   // global column index
      }
      ++base;
    }
  }
  __syncthreads();
  const int L2 = (total < CAP) ? total : CAP;

  // ---- deterministic psum + write normalized weights ----
  float ps = 0.0f;
  for (int i = t; i < L2; i += 256) ps += pb[i];
#pragma unroll
  for (int off = 32; off; off >>= 1) ps += __shfl_xor(ps, off);
  if (l == 0) wsum[w] = ps;
  __syncthreads();
  const float inv = 1.0f / (wsum[0] + wsum[1] + wsum[2] + wsum[3]);
  for (int i = t; i < L2; i += 256) {
    wts[(size_t)grow * CAP + i] = pb[i] * inv;
    idx[(size_t)grow * CAP + i] = jb[i];
  }
  if (t == 0) cnt[grow] = L2;
}

// ---------------------------------------------------------------------------
// Sparse AV: out[row][t] = sum_i wts[row][i] * V[idx[row][i]][t]
// ---------------------------------------------------------------------------
__global__ __launch_bounds__(256)
void sparse_av(const float* __restrict__ V, const float* __restrict__ wts,
               const int* __restrict__ idx, const int* __restrict__ cnt,
               float* __restrict__ out)
{
  __shared__ float wl[CAP];
  __shared__ int   jl[CAP];
  const int t = threadIdx.x;
  const int row = blockIdx.x;
  const int L = cnt[row];
  if (t < CAP && t < L) {
    wl[t] = wts[(size_t)row * CAP + t];
    jl[t] = idx[(size_t)row * CAP + t];
  }
  __syncthreads();
  float acc = 0.0f;
  for (int i = 0; i < L; ++i)
    acc = fmaf(wl[i], V[(size_t)jl[i] * DD + t], acc);
  out[(size_t)row * DD + t] = acc;
}

// ---------------------------------------------------------------------------
extern "C" void kernel_launch(void* const* d_in, const int* in_sizes, int n_in,
                              void* d_out, int out_size, void* d_ws, size_t ws_size,
                              hipStream_t stream)
{
  const float* X    = (const float*)d_in[0];
  const float* Wq   = (const float*)d_in[1];
  const float* bq   = (const float*)d_in[2];
  const float* Wk   = (const float*)d_in[3];
  const float* bk   = (const float*)d_in[4];
  const float* Wv   = (const float*)d_in[5];
  const float* bv   = (const float*)d_in[6];
  const float* temp = (const float*)d_in[7];
  float* out = (float*)d_out;
  float* ws  = (float*)d_ws;

  const size_t avail = ws_size / sizeof(float);

  const size_t szQK  = (size_t)NN * DD;          // 2M floats each
  const size_t szHL  = (size_t)NN * 768 / 2;     // f16 hi/lo buf in float units
  const size_t szWts = (size_t)NN * CAP;
  const size_t szIdx = (size_t)NN * CAP;
  const size_t szCnt = NN;
  const size_t fixed = 2 * szQK + 2 * szHL + szWts + szIdx + szCnt;

  size_t o = 0;
  float* Kbuf = ws + o; o += szQK;               // K f32, later reused as V
  float* Qbuf = ws + o; o += szQK;               // Q f32 (dead after cvt)
  f16*   Qs   = (f16*)(ws + o); o += szHL;
  f16*   Ks   = (f16*)(ws + o); o += szHL;
  float* wts  = ws + o; o += szWts;
  int*   idxb = (int*)(ws + o); o += szIdx;
  int*   cntb = (int*)(ws + o); o += szCnt;

  if (avail <= fixed + (size_t)128 * NN) return;
  int CR = (int)(((avail - fixed) / NN) / 128) * 128;
  if (CR > NN) CR = NN;
  float* Sc = ws + o;                             // CR x NN f32 score chunk

  dim3 blk(256);

  // K, Q projections (f32)
  gemm_nt_f32<<<dim3(NN/128, DD/128), blk, 0, stream>>>(X, Wk, Kbuf, DD, bk);
  gemm_nt_f32<<<dim3(NN/128, DD/128), blk, 0, stream>>>(X, Wq, Qbuf, DD, bq);
  // f16 hi/lo split (K-dim 768 layout)
  cvt_hilo<<<dim3((NN * DD) / 256), blk, 0, stream>>>(Qbuf, Kbuf, Qs, Ks);
  // V projection reuses Qbuf (Q f32 dead after cvt)
  float* Vbuf = Qbuf;
  gemm_nt_f32<<<dim3(NN/128, DD/128), blk, 0, stream>>>(X, Wv, Vbuf, DD, bv);

  for (int r0 = 0; r0 < NN; r0 += CR) {
    const int rows = (NN - r0 < CR) ? (NN - r0) : CR;
    gemm_scores_f16<<<dim3(rows/128, NN/128), blk, 0, stream>>>(
        Qs + (size_t)r0 * 768, Ks, Sc, temp, r0);
    topk_softmax2<<<dim3(rows), blk, 0, stream>>>(Sc, r0, wts, idxb, cntb);
  }

  sparse_av<<<dim3(NN), blk, 0, stream>>>(Vbuf, wts, idxb, cntb, out);
}